// Round 3
// baseline (326.561 us; speedup 1.0000x reference)
//
#include <hip/hip_runtime.h>
#include <stdint.h>

#define KNB 16
#define CAP 512      // survivor capacity per query (expected ~60-110)
#define QB  32       // queries per knn block
#define KT  512      // knn block threads (8 waves)

typedef short short8 __attribute__((ext_vector_type(8)));
typedef float floatx4 __attribute__((ext_vector_type(4)));

__device__ __forceinline__ unsigned short f2bf(float x) {
  union { float f; uint32_t u; } v; v.f = x;
  uint32_t u = v.u + 0x7FFFu + ((v.u >> 16) & 1u);   // RNE
  return (unsigned short)(u >> 16);
}
__device__ __forceinline__ float bf2f(unsigned short b) {
  return __uint_as_float(((uint32_t)b) << 16);
}

// ---------------------------------------------------------------------------
// prep: xb = bf16(x); pos4 = {x,y,z,pp}; bpanel = per-point MFMA B-column
// (split-precision); Wt = bf16 W_att^T.
// B k-slots: {ph.x,ph.y,ph.z, ph.x,ph.y,ph.z, pl.x,pl.y | pl.z, pph, ppl, 1, 1, 0,0,0}
// ---------------------------------------------------------------------------
__global__ void prep_kernel(const float* __restrict__ x,
                            const float* __restrict__ pos,
                            const float* __restrict__ W_att,
                            unsigned short* __restrict__ xb,
                            float4* __restrict__ pos4,
                            unsigned short* __restrict__ bpanel,
                            unsigned short* __restrict__ Wt, int N) {
  int id = blockIdx.x * 256 + threadIdx.x;
  int nx8 = N * 8;   // ids converting 8 x-floats each
  if (id < nx8) {
    const float4* src = (const float4*)x + (size_t)id * 2;
    float4 a = src[0], b = src[1];
    short8 v;
    v[0] = (short)f2bf(a.x); v[1] = (short)f2bf(a.y);
    v[2] = (short)f2bf(a.z); v[3] = (short)f2bf(a.w);
    v[4] = (short)f2bf(b.x); v[5] = (short)f2bf(b.y);
    v[6] = (short)f2bf(b.z); v[7] = (short)f2bf(b.w);
    *(short8*)(xb + (size_t)id * 8) = v;
  } else if (id < nx8 + N) {
    int j = id - nx8;
    float px = pos[3 * j], py = pos[3 * j + 1], pz = pos[3 * j + 2];
    float pp = fmaf(px, px, fmaf(py, py, pz * pz));
    pos4[j] = make_float4(px, py, pz, pp);
    unsigned short hx = f2bf(px), hy = f2bf(py), hz = f2bf(pz);
    unsigned short lx = f2bf(px - bf2f(hx)), ly = f2bf(py - bf2f(hy)),
                   lz = f2bf(pz - bf2f(hz));
    unsigned short hp = f2bf(pp), lp = f2bf(pp - bf2f(hp));
    short8 b0, b1;
    b0[0] = hx; b0[1] = hy; b0[2] = hz; b0[3] = hx;
    b0[4] = hy; b0[5] = hz; b0[6] = lx; b0[7] = ly;
    b1[0] = lz; b1[1] = hp; b1[2] = lp; b1[3] = (short)0x3F80;
    b1[4] = (short)0x3F80; b1[5] = 0; b1[6] = 0; b1[7] = 0;
    *(short8*)(bpanel + (size_t)j * 16)     = b0;
    *(short8*)(bpanel + (size_t)j * 16 + 8) = b1;
  } else if (id < nx8 + N + 128 * 128) {
    int t = id - nx8 - N;
    int c = t >> 7, f = t & 127;
    Wt[f * 128 + c] = f2bf(W_att[t]);
  }
}

// ---------------------------------------------------------------------------
// knn: MFMA threshold-select. t_mfma ~ d2, |err| <= eps_q. tau = max of 16
// disjoint group mins (8 waves x 2 col-halves); collect t <= tau + 2 eps;
// exact fp32 arbitration in pass 3 (bit-identical to R2's formula).
// A k-slots: {sh.x,sh.y,sh.z, sl.x,sl.y,sl.z, sh.x,sh.y | sh.z, 1, 1, qqh, qql, 0,0,0}
// where s = -2q.
// ---------------------------------------------------------------------------
__global__ __launch_bounds__(KT) void knn_kernel(
    const float4* __restrict__ pos4, const unsigned short* __restrict__ bpanel,
    const int* __restrict__ idx, int* __restrict__ nbr, int N, int M) {
  __shared__ uint32_t cand[QB][CAP];
  __shared__ int cnt[QB];
  __shared__ float gmin[QB][16];
  __shared__ float tau_adj[QB];
  __shared__ float4 qpos_s[QB];
  __shared__ float eps_s[QB];

  const int tid = threadIdx.x, wid = tid >> 6, lane = tid & 63;
  const int col = lane & 15, quad = lane >> 4;
  const int q0 = blockIdx.x * QB;
  const int ntiles = N / 16;              // N divisible by 16 (30000/16=1875)
  const int tpw = (ntiles + 7) / 8;
  const int t0 = wid * tpw;
  const int t1 = (t0 + tpw < ntiles) ? t0 + tpw : ntiles;

  if (tid < QB) cnt[tid] = 0;

  // ---- A-frag setup: each lane builds frags for its 2 query rows ----
  short8 afr[2];
#pragma unroll
  for (int at = 0; at < 2; ++at) {
    int m = q0 + at * 16 + col;
    if (m >= M) m = M - 1;
    int ii = idx[m];
    float4 qp = pos4[ii];
    float sx = -2.f * qp.x, sy = -2.f * qp.y, sz = -2.f * qp.z;
    unsigned short shx = f2bf(sx), shy = f2bf(sy), shz = f2bf(sz);
    unsigned short slx = f2bf(sx - bf2f(shx)), sly = f2bf(sy - bf2f(shy)),
                   slz = f2bf(sz - bf2f(shz));
    float qq = qp.w;
    unsigned short qh = f2bf(qq), ql = f2bf(qq - bf2f(qh));
    short8 a = {0, 0, 0, 0, 0, 0, 0, 0};
    if (quad == 0) {
      a[0] = (short)shx; a[1] = (short)shy; a[2] = (short)shz;
      a[3] = (short)slx; a[4] = (short)sly; a[5] = (short)slz;
      a[6] = (short)shx; a[7] = (short)shy;
    } else if (quad == 1) {
      a[0] = (short)shz; a[1] = (short)0x3F80; a[2] = (short)0x3F80;
      a[3] = (short)qh;  a[4] = (short)ql;
    }
    afr[at] = a;
    if (wid == 0 && quad == 0) {
      qpos_s[at * 16 + col] = make_float4(qp.x, qp.y, qp.z, qq);
      float qmax = fmaxf(fabsf(qp.x), fmaxf(fabsf(qp.y), fabsf(qp.z)));
      eps_s[at * 16 + col] = 1e-4f * (1.f + qmax) * (1.f + qmax) + 5e-5f;
    }
  }

  const floatx4 zero4 = {0.f, 0.f, 0.f, 0.f};
  const short8 bz = {0, 0, 0, 0, 0, 0, 0, 0};

  // ---- pass 1: per-(lane,reg) t-mins over this wave's tile range ----
  floatx4 tm0 = {3.4e38f, 3.4e38f, 3.4e38f, 3.4e38f}, tm1 = tm0;
  {
    short8 bcur = bz;
    if (t0 < t1 && quad < 2)
      bcur = *(const short8*)(bpanel + ((size_t)t0 * 256 + col * 16 + quad * 8));
    for (int t = t0; t < t1; ++t) {
      short8 bnext = bz;
      if (t + 1 < t1 && quad < 2)
        bnext = *(const short8*)(bpanel +
                                 ((size_t)(t + 1) * 256 + col * 16 + quad * 8));
      floatx4 c0 = __builtin_amdgcn_mfma_f32_16x16x32_bf16(afr[0], bcur, zero4, 0, 0, 0);
      floatx4 c1 = __builtin_amdgcn_mfma_f32_16x16x32_bf16(afr[1], bcur, zero4, 0, 0, 0);
#pragma unroll
      for (int r = 0; r < 4; ++r) {
        tm0[r] = fminf(tm0[r], c0[r]);
        tm1[r] = fminf(tm1[r], c1[r]);
      }
      bcur = bnext;
    }
  }
  // reduce cols to 2 groups of 8 per wave (xor 1,2,4 within the 16-col group)
#pragma unroll
  for (int r = 0; r < 4; ++r) {
    float v0 = tm0[r], v1 = tm1[r];
    v0 = fminf(v0, __shfl_xor(v0, 1)); v1 = fminf(v1, __shfl_xor(v1, 1));
    v0 = fminf(v0, __shfl_xor(v0, 2)); v1 = fminf(v1, __shfl_xor(v1, 2));
    v0 = fminf(v0, __shfl_xor(v0, 4)); v1 = fminf(v1, __shfl_xor(v1, 4));
    tm0[r] = v0; tm1[r] = v1;
  }
  if ((lane & 7) == 0) {
    int g = wid * 2 + ((lane >> 3) & 1);
#pragma unroll
    for (int r = 0; r < 4; ++r) {
      gmin[quad * 4 + r][g]      = tm0[r];
      gmin[16 + quad * 4 + r][g] = tm1[r];
    }
  }
  __syncthreads();
  if (tid < QB) {
    float t = gmin[tid][0];
#pragma unroll
    for (int g = 1; g < 16; ++g) t = fmaxf(t, gmin[tid][g]);
    tau_adj[tid] = t + 2.f * eps_s[tid] + fabsf(t) * 1e-6f + 1e-7f;
  }
  __syncthreads();

  float taur0[4], taur1[4];
#pragma unroll
  for (int r = 0; r < 4; ++r) {
    taur0[r] = tau_adj[quad * 4 + r];
    taur1[r] = tau_adj[16 + quad * 4 + r];
  }

  // ---- pass 2: re-stream, collect survivor indices ----
  {
    short8 bcur = bz;
    if (t0 < t1 && quad < 2)
      bcur = *(const short8*)(bpanel + ((size_t)t0 * 256 + col * 16 + quad * 8));
    for (int t = t0; t < t1; ++t) {
      short8 bnext = bz;
      if (t + 1 < t1 && quad < 2)
        bnext = *(const short8*)(bpanel +
                                 ((size_t)(t + 1) * 256 + col * 16 + quad * 8));
      floatx4 c0 = __builtin_amdgcn_mfma_f32_16x16x32_bf16(afr[0], bcur, zero4, 0, 0, 0);
      floatx4 c1 = __builtin_amdgcn_mfma_f32_16x16x32_bf16(afr[1], bcur, zero4, 0, 0, 0);
      int jme = t * 16 + col;
#pragma unroll
      for (int r = 0; r < 4; ++r) {
        if (c0[r] <= taur0[r]) {
          int ml = quad * 4 + r;
          int sl = atomicAdd(&cnt[ml], 1);
          if (sl < CAP) cand[ml][sl] = (uint32_t)jme;
        }
        if (c1[r] <= taur1[r]) {
          int ml = 16 + quad * 4 + r;
          int sl = atomicAdd(&cnt[ml], 1);
          if (sl < CAP) cand[ml][sl] = (uint32_t)jme;
        }
      }
      bcur = bnext;
    }
  }
  __syncthreads();

  // ---- pass 3: one wave per 4 queries; exact fp32 d2, extract 16 smallest ----
#pragma unroll
  for (int i = 0; i < 4; ++i) {
    int ql = wid * 4 + i;
    int mq = q0 + ql;
    int nc = cnt[ql]; if (nc > CAP) nc = CAP;
    int nch = (nc + 63) >> 6;
    float4 qp = qpos_s[ql];
    unsigned long long c[CAP / 64];
#pragma unroll
    for (int ch = 0; ch < CAP / 64; ++ch) c[ch] = ~0ull;
    for (int ch = 0; ch < nch; ++ch) {
      int s = ch * 64 + lane;
      if (s < nc) {
        uint32_t j = cand[ql][s];
        float4 pj = pos4[j];
        float dot = fmaf(qp.x, pj.x, fmaf(qp.y, pj.y, qp.z * pj.z));
        float tt = fmaf(-2.f, dot, pj.w);
        float d2 = fmaxf(qp.w + tt, 0.f);
        c[ch] = ((unsigned long long)__float_as_uint(d2) << 32) | j;
      }
    }
#pragma unroll
    for (int r = 0; r < KNB; ++r) {
      unsigned long long mn = c[0];
#pragma unroll
      for (int ch = 1; ch < CAP / 64; ++ch) mn = (c[ch] < mn) ? c[ch] : mn;
#pragma unroll
      for (int off = 1; off < 64; off <<= 1) {
        unsigned long long o = __shfl_xor(mn, off);
        mn = (o < mn) ? o : mn;
      }
      if (mq < M && lane == 0) nbr[mq * KNB + r] = (int)(uint32_t)mn;
#pragma unroll
      for (int ch = 0; ch < CAP / 64; ++ch)
        if (c[ch] == mn) c[ch] = ~0ull;
    }
  }
}

// ---------------------------------------------------------------------------
// mid: 8 queries / 256-thread block. Batched bf16 x-gather, LocSE, bf16-MFMA
// attention matvec (Wt frags shared across 2 queries/wave), softmax + mean.
// ---------------------------------------------------------------------------
__global__ __launch_bounds__(256) void mid_kernel(
    const unsigned short* __restrict__ xb, const float4* __restrict__ pos4,
    const int* __restrict__ idx, const float* __restrict__ W_pos,
    const float* __restrict__ b_pos, const unsigned short* __restrict__ Wt,
    const float* __restrict__ b_att, const int* __restrict__ nbr,
    float* __restrict__ aggr, int M) {
  __shared__ __align__(16) unsigned short fijb[8][16][136];  // 16B-aligned rows
  __shared__ int nbr_s[128];
  __shared__ float4 qpos_s[8];

  const int tid = threadIdx.x;
  const int wid = tid >> 6, lane = tid & 63;
  const int col = lane & 15, quad = lane >> 4;
  const int b = blockIdx.x;

  if (tid < 128) {
    int mq = b * 8 + (tid >> 4); if (mq >= M) mq = M - 1;
    nbr_s[tid] = nbr[mq * 16 + (tid & 15)];
  }
  if (tid < 8) {
    int mq = b * 8 + tid; if (mq >= M) mq = M - 1;
    qpos_s[tid] = pos4[idx[mq]];
  }
  float wp[10];
#pragma unroll
  for (int t = 0; t < 10; ++t) wp[t] = W_pos[t * 64 + lane];
  float bp = b_pos[lane];
  __syncthreads();

  // phase 1a: x gather (bf16 rows), 2 threads per (q,k) row
  {
    int rr = tid >> 1, h = tid & 1;
    int jn = nbr_s[rr];
    const short8* src = (const short8*)(xb + ((size_t)jn << 6) + (h << 5));
    short8 v0 = src[0], v1 = src[1], v2 = src[2], v3 = src[3];
    short8* dst = (short8*)&fijb[rr >> 4][rr & 15][h * 32];
    dst[0] = v0; dst[1] = v1; dst[2] = v2; dst[3] = v3;
  }
  // phase 1b: LocSE rij (bf16), wave handles 2 queries, lane = channel
#pragma unroll
  for (int qi = 0; qi < 2; ++qi) {
    int q = wid * 2 + qi;
    float4 qp = qpos_s[q];
#pragma unroll 4
    for (int k = 0; k < 16; ++k) {
      int jn = nbr_s[q * 16 + k];
      float4 pj = pos4[jn];
      float vx = qp.x - pj.x, vy = qp.y - pj.y, vz = qp.z - pj.z;
      float dd = sqrtf(fmaf(vx, vx, fmaf(vy, vy, vz * vz)));
      float r = bp;
      r = fmaf(qp.x, wp[0], r); r = fmaf(qp.y, wp[1], r); r = fmaf(qp.z, wp[2], r);
      r = fmaf(pj.x, wp[3], r); r = fmaf(pj.y, wp[4], r); r = fmaf(pj.z, wp[5], r);
      r = fmaf(vx, wp[6], r);  r = fmaf(vy, wp[7], r);  r = fmaf(vz, wp[8], r);
      r = fmaf(dd, wp[9], r);
      r = fmaxf(r, 0.f);
      fijb[q][k][64 + lane] = f2bf(r);
    }
  }
  __syncthreads();

  // phase 2: per wave, 2 queries; Wt B-frags shared
#pragma unroll 1
  for (int qi = 0; qi < 2; ++qi) {
    int q = wid * 2 + qi;
    int mq = b * 8 + q;

    short8 af[4];
#pragma unroll
    for (int cs = 0; cs < 4; ++cs)
      af[cs] = *(const short8*)&fijb[q][col][cs * 32 + quad * 8];

    floatx4 acc[8];
    float bav = 0.f;
#pragma unroll
    for (int ft = 0; ft < 8; ++ft) {
      bav = b_att[ft * 16 + col];
      floatx4 a = {bav, bav, bav, bav};
#pragma unroll
      for (int cs = 0; cs < 4; ++cs) {
        short8 bfrag =
            *(const short8*)&Wt[(ft * 16 + col) * 128 + cs * 32 + quad * 8];
        a = __builtin_amdgcn_mfma_f32_16x16x32_bf16(af[cs], bfrag, a, 0, 0, 0);
      }
      acc[ft] = a;
    }

    // softmax over 128 features per row (row = neighbor k = quad*4+r)
    float rowmax[4], rowinv[4];
#pragma unroll
    for (int r = 0; r < 4; ++r) {
      float mx = acc[0][r];
#pragma unroll
      for (int ft = 1; ft < 8; ++ft) mx = fmaxf(mx, acc[ft][r]);
      mx = fmaxf(mx, __shfl_xor(mx, 1));
      mx = fmaxf(mx, __shfl_xor(mx, 2));
      mx = fmaxf(mx, __shfl_xor(mx, 4));
      mx = fmaxf(mx, __shfl_xor(mx, 8));
      float sm = 0.f;
#pragma unroll
      for (int ft = 0; ft < 8; ++ft) sm += __expf(acc[ft][r] - mx);
      sm += __shfl_xor(sm, 1);
      sm += __shfl_xor(sm, 2);
      sm += __shfl_xor(sm, 4);
      sm += __shfl_xor(sm, 8);
      rowmax[r] = mx;
      rowinv[r] = 1.0f / sm;
    }

    // mean over k: s * fij, rows in-lane then cross-quad
#pragma unroll
    for (int ft = 0; ft < 8; ++ft) {
      float ap = 0.f;
#pragma unroll
      for (int r = 0; r < 4; ++r) {
        float s = __expf(acc[ft][r] - rowmax[r]) * rowinv[r];
        float fv = bf2f(fijb[q][quad * 4 + r][ft * 16 + col]);
        ap = fmaf(s, fv, ap);
      }
      ap += __shfl_xor(ap, 16);
      ap += __shfl_xor(ap, 32);
      if (quad == 0 && mq < M)
        aggr[mq * 128 + ft * 16 + col] = ap * (1.0f / 16.0f);
    }
  }
}

// ---------------------------------------------------------------------------
// out = relu(aggr @ W_glob + b_glob)
// ---------------------------------------------------------------------------
__global__ __launch_bounds__(256) void out_kernel(
    const float* __restrict__ aggr, const float* __restrict__ W_glob,
    const float* __restrict__ b_glob, float* __restrict__ out, int M) {
  __shared__ float ag[16][128];
  const int tid = threadIdx.x;
  const int mbase = blockIdx.x * 16;
  for (int s = tid; s < 16 * 128; s += 256) {
    int r = s >> 7, cc = s & 127;
    int m = mbase + r;
    ((float*)ag)[s] = (m < M) ? aggr[m * 128 + cc] : 0.0f;
  }
  __syncthreads();
  const int f = tid & 127, h = tid >> 7;
  float acc[8];
  float bg = b_glob[f];
#pragma unroll
  for (int i = 0; i < 8; ++i) acc[i] = bg;
  for (int c = 0; c < 128; c += 4) {
    float w0 = W_glob[(c + 0) * 128 + f];
    float w1 = W_glob[(c + 1) * 128 + f];
    float w2 = W_glob[(c + 2) * 128 + f];
    float w3 = W_glob[(c + 3) * 128 + f];
#pragma unroll
    for (int i = 0; i < 8; ++i) {
      const floatx4 a4 = *(const floatx4*)&ag[h * 8 + i][c];
      acc[i] += a4[0] * w0 + a4[1] * w1 + a4[2] * w2 + a4[3] * w3;
    }
  }
#pragma unroll
  for (int i = 0; i < 8; ++i) {
    int m = mbase + h * 8 + i;
    if (m < M) out[m * 128 + f] = fmaxf(acc[i], 0.0f);
  }
}

// ---------------------------------------------------------------------------
extern "C" void kernel_launch(void* const* d_in, const int* in_sizes, int n_in,
                              void* d_out, int out_size, void* d_ws,
                              size_t ws_size, hipStream_t stream) {
  const float* x      = (const float*)d_in[0];
  const float* pos    = (const float*)d_in[1];
  const int*   idx    = (const int*)d_in[2];
  const float* W_pos  = (const float*)d_in[3];
  const float* b_pos  = (const float*)d_in[4];
  const float* W_att  = (const float*)d_in[5];
  const float* b_att  = (const float*)d_in[6];
  const float* W_glob = (const float*)d_in[7];
  const float* b_glob = (const float*)d_in[8];
  float* out = (float*)d_out;

  const int N = in_sizes[1] / 3;
  const int M = in_sizes[2];

  char* ws = (char*)d_ws;
  size_t o = 0;
  float4* pos4 = (float4*)(ws + o);            o += ((size_t)N * 16 + 255) & ~(size_t)255;
  unsigned short* xb = (unsigned short*)(ws + o); o += ((size_t)N * 64 * 2 + 255) & ~(size_t)255;
  unsigned short* bpanel = (unsigned short*)(ws + o); o += ((size_t)N * 16 * 2 + 255) & ~(size_t)255;
  unsigned short* Wt = (unsigned short*)(ws + o); o += (128 * 128 * 2 + 255) & ~(size_t)255;
  int* nbr = (int*)(ws + o);                   o += (((size_t)M * KNB * 4) + 255) & ~(size_t)255;
  float* aggr = (float*)(ws + o);

  int prep_ids = N * 8 + N + 128 * 128;
  prep_kernel<<<(prep_ids + 255) / 256, 256, 0, stream>>>(x, pos, W_att, xb,
                                                          pos4, bpanel, Wt, N);
  knn_kernel<<<(M + QB - 1) / QB, KT, 0, stream>>>(pos4, bpanel, idx, nbr, N, M);
  mid_kernel<<<(M + 7) / 8, 256, 0, stream>>>(xb, pos4, idx, W_pos, b_pos, Wt,
                                              b_att, nbr, aggr, M);
  out_kernel<<<(M + 15) / 16, 256, 0, stream>>>(aggr, W_glob, b_glob, out, M);
}

// Round 4
// 229.086 us; speedup vs baseline: 1.4255x; 1.4255x over previous
//
#include <hip/hip_runtime.h>
#include <stdint.h>

#define KQ    8      // queries per KNN block
#define CAP   512    // survivor capacity per query (expected ~54)
#define KNN_T 256
#define KNB   16

typedef short short8 __attribute__((ext_vector_type(8)));
typedef float floatx4 __attribute__((ext_vector_type(4)));
typedef float floatx2 __attribute__((ext_vector_type(2)));

__device__ __forceinline__ unsigned short f2bf(float x) {
  union { float f; uint32_t u; } v; v.f = x;
  uint32_t u = v.u + 0x7FFFu + ((v.u >> 16) & 1u);   // RNE
  return (unsigned short)(u >> 16);
}
__device__ __forceinline__ float bf2f(unsigned short b) {
  return __uint_as_float(((uint32_t)b) << 16);
}

static __device__ __forceinline__ floatx2 fma2(floatx2 a, floatx2 b, floatx2 c) {
#if __has_builtin(__builtin_elementwise_fma)
  return __builtin_elementwise_fma(a, b, c);    // -> v_pk_fma_f32
#else
  floatx2 r; r[0] = fmaf(a[0], b[0], c[0]); r[1] = fmaf(a[1], b[1], c[1]);
  return r;
#endif
}
static __device__ __forceinline__ floatx2 min2(floatx2 a, floatx2 b) {
#if __has_builtin(__builtin_elementwise_min)
  return __builtin_elementwise_min(a, b);
#else
  floatx2 r; r[0] = fminf(a[0], b[0]); r[1] = fminf(a[1], b[1]);
  return r;
#endif
}
static __device__ __forceinline__ floatx2 sp2(float v) {
  floatx2 r; r[0] = v; r[1] = v; return r;
}

// ---------------------------------------------------------------------------
// prep: xb = bf16(x); pos4 = {x,y,z,pp}; pospk = pair-SoA
// {x0,x1,y0,y1,z0,z1,pp0,pp1} with pp=3e38 sentinels to Npad2; Wt = bf16 W^T.
// ---------------------------------------------------------------------------
__global__ void prep_kernel(const float* __restrict__ x,
                            const float* __restrict__ pos,
                            const float* __restrict__ W_att,
                            unsigned short* __restrict__ xb,
                            float4* __restrict__ pos4,
                            float* __restrict__ pospk,
                            unsigned short* __restrict__ Wt, int N, int Npad2) {
  int id = blockIdx.x * 256 + threadIdx.x;
  int nx8 = N * 8;
  if (id < nx8) {
    const float4* src = (const float4*)x + (size_t)id * 2;
    float4 a = src[0], b = src[1];
    short8 v;
    v[0] = (short)f2bf(a.x); v[1] = (short)f2bf(a.y);
    v[2] = (short)f2bf(a.z); v[3] = (short)f2bf(a.w);
    v[4] = (short)f2bf(b.x); v[5] = (short)f2bf(b.y);
    v[6] = (short)f2bf(b.z); v[7] = (short)f2bf(b.w);
    *(short8*)(xb + (size_t)id * 8) = v;
  } else if (id < nx8 + Npad2) {
    int j = id - nx8;
    float px = 0.f, py = 0.f, pz = 0.f, pp = 3.0e38f;
    if (j < N) {
      px = pos[3 * j]; py = pos[3 * j + 1]; pz = pos[3 * j + 2];
      pp = fmaf(px, px, fmaf(py, py, pz * pz));
      pos4[j] = make_float4(px, py, pz, pp);
    }
    int pair = j >> 1, h = j & 1;
    float* dst = pospk + (size_t)pair * 8;
    dst[0 + h] = px; dst[2 + h] = py; dst[4 + h] = pz; dst[6 + h] = pp;
  } else if (id < nx8 + Npad2 + 128 * 128) {
    int t = id - nx8 - Npad2;
    int c = t >> 7, f = t & 127;
    Wt[f * 128 + c] = f2bf(W_att[t]);
  }
}

// ---------------------------------------------------------------------------
// knn: scalar threshold-select with packed-f32 math, 2 points/lane/iter.
// t = pp + s.p (s = -2q); top-k by t == top-k by d2 (qq row-constant).
// tau = max of 16 disjoint group mins >= t_(16). Exact f32 d2 arbitration
// on survivors in pass 3 (formula identical to passing R2/R3 kernels).
// ---------------------------------------------------------------------------
__global__ __launch_bounds__(KNN_T) void knn_kernel(
    const float4* __restrict__ pos4, const float4* __restrict__ pospk4,
    const int* __restrict__ idx, int* __restrict__ nbr, int Npad2, int M) {
  __shared__ uint32_t cand[KQ][CAP];
  __shared__ int cnt[KQ];
  __shared__ float gmin[KQ][16];
  __shared__ float tau_s[KQ];
  __shared__ float4 qpos_s[KQ];

  const int tid = threadIdx.x;
  const int q0  = blockIdx.x * KQ;
  const int iters = Npad2 >> 9;   // 512 points per block-iter

  float sx[KQ], sy[KQ], sz[KQ];
#pragma unroll
  for (int qi = 0; qi < KQ; ++qi) {
    int m = q0 + qi; if (m >= M) m = M - 1;
    float4 qp = pos4[idx[m]];
    sx[qi] = -2.f * qp.x; sy[qi] = -2.f * qp.y; sz[qi] = -2.f * qp.z;
    if (tid == qi) qpos_s[qi] = qp;
  }
  if (tid < KQ) cnt[tid] = 0;

  // ---- pass 1: packed per-lane t-mins, prefetched point stream ----
  floatx2 tmn[KQ];
#pragma unroll
  for (int qi = 0; qi < KQ; ++qi) tmn[qi] = sp2(3.4e38f);
  {
    float4 a = pospk4[tid * 2], b = pospk4[tid * 2 + 1];
    for (int it = 0; it < iters; ++it) {
      float4 an = a, bn = b;
      if (it + 1 < iters) {
        int nb = (it + 1) * 512 + tid * 2;
        an = pospk4[nb]; bn = pospk4[nb + 1];
      }
      floatx2 X, Y, Z, W;
      X[0] = a.x; X[1] = a.y; Y[0] = a.z; Y[1] = a.w;
      Z[0] = b.x; Z[1] = b.y; W[0] = b.z; W[1] = b.w;
#pragma unroll
      for (int qi = 0; qi < KQ; ++qi) {
        floatx2 t = fma2(sp2(sx[qi]), X,
                         fma2(sp2(sy[qi]), Y, fma2(sp2(sz[qi]), Z, W)));
        tmn[qi] = min2(tmn[qi], t);
      }
      a = an; b = bn;
    }
  }
#pragma unroll
  for (int qi = 0; qi < KQ; ++qi) {
    float v = fminf(tmn[qi][0], tmn[qi][1]);
    v = fminf(v, __shfl_xor(v, 1));
    v = fminf(v, __shfl_xor(v, 2));
    v = fminf(v, __shfl_xor(v, 4));
    v = fminf(v, __shfl_xor(v, 8));
    if ((tid & 15) == 0) gmin[qi][tid >> 4] = v;
  }
  __syncthreads();
  if (tid < KQ) {
    float t = gmin[tid][0];
#pragma unroll
    for (int g = 1; g < 16; ++g) t = fmaxf(t, gmin[tid][g]);
    tau_s[tid] = t + fabsf(t) * 1e-6f + 1e-7f;   // paranoia margin
  }
  __syncthreads();
  float tau[KQ];
#pragma unroll
  for (int qi = 0; qi < KQ; ++qi) tau[qi] = tau_s[qi];

  // ---- pass 2: re-stream, collect survivor indices ----
  {
    float4 a = pospk4[tid * 2], b = pospk4[tid * 2 + 1];
    for (int it = 0; it < iters; ++it) {
      float4 an = a, bn = b;
      if (it + 1 < iters) {
        int nb = (it + 1) * 512 + tid * 2;
        an = pospk4[nb]; bn = pospk4[nb + 1];
      }
      floatx2 X, Y, Z, W;
      X[0] = a.x; X[1] = a.y; Y[0] = a.z; Y[1] = a.w;
      Z[0] = b.x; Z[1] = b.y; W[0] = b.z; W[1] = b.w;
      const int j0 = (it * 256 + tid) * 2;
#pragma unroll
      for (int qi = 0; qi < KQ; ++qi) {
        floatx2 t = fma2(sp2(sx[qi]), X,
                         fma2(sp2(sy[qi]), Y, fma2(sp2(sz[qi]), Z, W)));
        if (fminf(t[0], t[1]) <= tau[qi]) {
          if (t[0] <= tau[qi]) {
            int sl = atomicAdd(&cnt[qi], 1);
            if (sl < CAP) cand[qi][sl] = (uint32_t)j0;
          }
          if (t[1] <= tau[qi]) {
            int sl = atomicAdd(&cnt[qi], 1);
            if (sl < CAP) cand[qi][sl] = (uint32_t)(j0 + 1);
          }
        }
      }
      a = an; b = bn;
    }
  }
  __syncthreads();

  // ---- pass 3: wave handles 2 queries; exact f32 d2, extract 16 smallest ----
  const int wv = tid >> 6, ln = tid & 63;
#pragma unroll
  for (int i = 0; i < 2; ++i) {
    int ql = wv * 2 + i;
    int mq = q0 + ql;
    int nc = cnt[ql]; if (nc > CAP) nc = CAP;
    float4 qp = qpos_s[ql];
    unsigned long long c[CAP / 64];
#pragma unroll
    for (int ch = 0; ch < CAP / 64; ++ch) c[ch] = ~0ull;
#pragma unroll
    for (int ch = 0; ch < CAP / 64; ++ch) {
      int s = ch * 64 + ln;
      if (s < nc) {
        uint32_t j = cand[ql][s];
        float4 pj = pos4[j];
        float dot = fmaf(qp.x, pj.x, fmaf(qp.y, pj.y, qp.z * pj.z));
        float tt  = fmaf(-2.f, dot, pj.w);
        float d2  = fmaxf(qp.w + tt, 0.f);
        c[ch] = ((unsigned long long)__float_as_uint(d2) << 32) | j;
      }
    }
#pragma unroll
    for (int r = 0; r < KNB; ++r) {
      unsigned long long mn = c[0];
#pragma unroll
      for (int ch = 1; ch < CAP / 64; ++ch) mn = (c[ch] < mn) ? c[ch] : mn;
#pragma unroll
      for (int off = 1; off < 64; off <<= 1) {
        unsigned long long o = __shfl_xor(mn, off);
        mn = (o < mn) ? o : mn;
      }
      if (mq < M && ln == 0) nbr[mq * KNB + r] = (int)(uint32_t)mn;
#pragma unroll
      for (int ch = 0; ch < CAP / 64; ++ch)
        if (c[ch] == mn) c[ch] = ~0ull;
    }
  }
}

// ---------------------------------------------------------------------------
// mid: 8 queries / 256-thread block (unchanged from passing R3 version).
// ---------------------------------------------------------------------------
__global__ __launch_bounds__(256) void mid_kernel(
    const unsigned short* __restrict__ xb, const float4* __restrict__ pos4,
    const int* __restrict__ idx, const float* __restrict__ W_pos,
    const float* __restrict__ b_pos, const unsigned short* __restrict__ Wt,
    const float* __restrict__ b_att, const int* __restrict__ nbr,
    float* __restrict__ aggr, int M) {
  __shared__ __align__(16) unsigned short fijb[8][16][136];
  __shared__ int nbr_s[128];
  __shared__ float4 qpos_s[8];

  const int tid = threadIdx.x;
  const int wid = tid >> 6, lane = tid & 63;
  const int col = lane & 15, quad = lane >> 4;
  const int b = blockIdx.x;

  if (tid < 128) {
    int mq = b * 8 + (tid >> 4); if (mq >= M) mq = M - 1;
    nbr_s[tid] = nbr[mq * 16 + (tid & 15)];
  }
  if (tid < 8) {
    int mq = b * 8 + tid; if (mq >= M) mq = M - 1;
    qpos_s[tid] = pos4[idx[mq]];
  }
  float wp[10];
#pragma unroll
  for (int t = 0; t < 10; ++t) wp[t] = W_pos[t * 64 + lane];
  float bp = b_pos[lane];
  __syncthreads();

  {
    int rr = tid >> 1, h = tid & 1;
    int jn = nbr_s[rr];
    const short8* src = (const short8*)(xb + ((size_t)jn << 6) + (h << 5));
    short8 v0 = src[0], v1 = src[1], v2 = src[2], v3 = src[3];
    short8* dst = (short8*)&fijb[rr >> 4][rr & 15][h * 32];
    dst[0] = v0; dst[1] = v1; dst[2] = v2; dst[3] = v3;
  }
#pragma unroll
  for (int qi = 0; qi < 2; ++qi) {
    int q = wid * 2 + qi;
    float4 qp = qpos_s[q];
#pragma unroll 4
    for (int k = 0; k < 16; ++k) {
      int jn = nbr_s[q * 16 + k];
      float4 pj = pos4[jn];
      float vx = qp.x - pj.x, vy = qp.y - pj.y, vz = qp.z - pj.z;
      float dd = sqrtf(fmaf(vx, vx, fmaf(vy, vy, vz * vz)));
      float r = bp;
      r = fmaf(qp.x, wp[0], r); r = fmaf(qp.y, wp[1], r); r = fmaf(qp.z, wp[2], r);
      r = fmaf(pj.x, wp[3], r); r = fmaf(pj.y, wp[4], r); r = fmaf(pj.z, wp[5], r);
      r = fmaf(vx, wp[6], r);  r = fmaf(vy, wp[7], r);  r = fmaf(vz, wp[8], r);
      r = fmaf(dd, wp[9], r);
      r = fmaxf(r, 0.f);
      fijb[q][k][64 + lane] = f2bf(r);
    }
  }
  __syncthreads();

#pragma unroll 1
  for (int qi = 0; qi < 2; ++qi) {
    int q = wid * 2 + qi;
    int mq = b * 8 + q;

    short8 af[4];
#pragma unroll
    for (int cs = 0; cs < 4; ++cs)
      af[cs] = *(const short8*)&fijb[q][col][cs * 32 + quad * 8];

    floatx4 acc[8];
#pragma unroll
    for (int ft = 0; ft < 8; ++ft) {
      float bav = b_att[ft * 16 + col];
      floatx4 a = {bav, bav, bav, bav};
#pragma unroll
      for (int cs = 0; cs < 4; ++cs) {
        short8 bfrag =
            *(const short8*)&Wt[(ft * 16 + col) * 128 + cs * 32 + quad * 8];
        a = __builtin_amdgcn_mfma_f32_16x16x32_bf16(af[cs], bfrag, a, 0, 0, 0);
      }
      acc[ft] = a;
    }

    float rowmax[4], rowinv[4];
#pragma unroll
    for (int r = 0; r < 4; ++r) {
      float mx = acc[0][r];
#pragma unroll
      for (int ft = 1; ft < 8; ++ft) mx = fmaxf(mx, acc[ft][r]);
      mx = fmaxf(mx, __shfl_xor(mx, 1));
      mx = fmaxf(mx, __shfl_xor(mx, 2));
      mx = fmaxf(mx, __shfl_xor(mx, 4));
      mx = fmaxf(mx, __shfl_xor(mx, 8));
      float sm = 0.f;
#pragma unroll
      for (int ft = 0; ft < 8; ++ft) sm += __expf(acc[ft][r] - mx);
      sm += __shfl_xor(sm, 1);
      sm += __shfl_xor(sm, 2);
      sm += __shfl_xor(sm, 4);
      sm += __shfl_xor(sm, 8);
      rowmax[r] = mx;
      rowinv[r] = 1.0f / sm;
    }

#pragma unroll
    for (int ft = 0; ft < 8; ++ft) {
      float ap = 0.f;
#pragma unroll
      for (int r = 0; r < 4; ++r) {
        float s = __expf(acc[ft][r] - rowmax[r]) * rowinv[r];
        float fv = bf2f(fijb[q][quad * 4 + r][ft * 16 + col]);
        ap = fmaf(s, fv, ap);
      }
      ap += __shfl_xor(ap, 16);
      ap += __shfl_xor(ap, 32);
      if (quad == 0 && mq < M)
        aggr[mq * 128 + ft * 16 + col] = ap * (1.0f / 16.0f);
    }
  }
}

// ---------------------------------------------------------------------------
// out = relu(aggr @ W_glob + b_glob)
// ---------------------------------------------------------------------------
__global__ __launch_bounds__(256) void out_kernel(
    const float* __restrict__ aggr, const float* __restrict__ W_glob,
    const float* __restrict__ b_glob, float* __restrict__ out, int M) {
  __shared__ float ag[16][128];
  const int tid = threadIdx.x;
  const int mbase = blockIdx.x * 16;
  for (int s = tid; s < 16 * 128; s += 256) {
    int r = s >> 7, cc = s & 127;
    int m = mbase + r;
    ((float*)ag)[s] = (m < M) ? aggr[m * 128 + cc] : 0.0f;
  }
  __syncthreads();
  const int f = tid & 127, h = tid >> 7;
  float acc[8];
  float bg = b_glob[f];
#pragma unroll
  for (int i = 0; i < 8; ++i) acc[i] = bg;
  for (int c = 0; c < 128; c += 4) {
    float w0 = W_glob[(c + 0) * 128 + f];
    float w1 = W_glob[(c + 1) * 128 + f];
    float w2 = W_glob[(c + 2) * 128 + f];
    float w3 = W_glob[(c + 3) * 128 + f];
#pragma unroll
    for (int i = 0; i < 8; ++i) {
      const floatx4 a4 = *(const floatx4*)&ag[h * 8 + i][c];
      acc[i] += a4[0] * w0 + a4[1] * w1 + a4[2] * w2 + a4[3] * w3;
    }
  }
#pragma unroll
  for (int i = 0; i < 8; ++i) {
    int m = mbase + h * 8 + i;
    if (m < M) out[m * 128 + f] = fmaxf(acc[i], 0.0f);
  }
}

// ---------------------------------------------------------------------------
extern "C" void kernel_launch(void* const* d_in, const int* in_sizes, int n_in,
                              void* d_out, int out_size, void* d_ws,
                              size_t ws_size, hipStream_t stream) {
  const float* x      = (const float*)d_in[0];
  const float* pos    = (const float*)d_in[1];
  const int*   idx    = (const int*)d_in[2];
  const float* W_pos  = (const float*)d_in[3];
  const float* b_pos  = (const float*)d_in[4];
  const float* W_att  = (const float*)d_in[5];
  const float* b_att  = (const float*)d_in[6];
  const float* W_glob = (const float*)d_in[7];
  const float* b_glob = (const float*)d_in[8];
  float* out = (float*)d_out;

  const int N = in_sizes[1] / 3;
  const int M = in_sizes[2];
  const int Npad2 = (N + 511) & ~511;

  char* ws = (char*)d_ws;
  size_t o = 0;
  float4* pos4 = (float4*)(ws + o);               o += ((size_t)N * 16 + 255) & ~(size_t)255;
  unsigned short* xb = (unsigned short*)(ws + o); o += ((size_t)N * 128 + 255) & ~(size_t)255;
  float* pospk = (float*)(ws + o);                o += ((size_t)Npad2 * 16 + 255) & ~(size_t)255;
  unsigned short* Wt = (unsigned short*)(ws + o); o += (128 * 128 * 2 + 255) & ~(size_t)255;
  int* nbr = (int*)(ws + o);                      o += (((size_t)M * KNB * 4) + 255) & ~(size_t)255;
  float* aggr = (float*)(ws + o);

  int prep_ids = N * 8 + Npad2 + 128 * 128;
  prep_kernel<<<(prep_ids + 255) / 256, 256, 0, stream>>>(
      x, pos, W_att, xb, pos4, pospk, Wt, N, Npad2);
  knn_kernel<<<(M + KQ - 1) / KQ, KNN_T, 0, stream>>>(
      pos4, (const float4*)pospk, idx, nbr, Npad2, M);
  mid_kernel<<<(M + 7) / 8, 256, 0, stream>>>(xb, pos4, idx, W_pos, b_pos, Wt,
                                              b_att, nbr, aggr, M);
  out_kernel<<<(M + 15) / 16, 256, 0, stream>>>(aggr, W_glob, b_glob, out, M);
}